// Round 1
// baseline (2300.874 us; speedup 1.0000x reference)
//
#include <hip/hip_runtime.h>

#define LDF 68   // padded row stride for 64-wide LDS tiles
#define LDT 68   // padded row stride for GEMM LDS tiles (16B aligned: 68*4=272)
#define EPSF 1e-8f

__device__ __forceinline__ float sigf(float x){ return 1.0f/(1.0f + __expf(-x)); }

// ---------------- init / reorder kernels ----------------
__global__ void reorder_gates(const float* __restrict__ src, float* __restrict__ dst,
                              int H, int K, int total){
  int idx = blockIdx.x*256 + threadIdx.x;
  if (idx >= total) return;
  int row = idx / K;
  int col = idx - row*K;
  int j = row >> 2, g = row & 3;
  dst[idx] = src[(size_t)(g*H + j)*K + col];
}

// WzP[(k>>2)*1024 + n*4 + (k&3)] = n<128 ? muW[n][k] : sigW[n-128][k]
__global__ void pack_wz(const float* __restrict__ muW, const float* __restrict__ sigW,
                        float* __restrict__ dst){
  int idx = blockIdx.x*256 + threadIdx.x;
  if (idx >= 512*256) return;
  int k = idx >> 8, n = idx & 255;
  float v = (n < 128) ? muW[n*512 + k] : sigW[(n-128)*512 + k];
  dst[(k>>2)*1024 + n*4 + (k&3)] = v;
}

__global__ void transpose_ww(const float* __restrict__ W, float* __restrict__ dst){
  int idx = blockIdx.x*256 + threadIdx.x;
  if (idx >= 512*64) return;
  int k = idx >> 6, n = idx & 63;
  dst[idx] = W[n*512 + k];
}

__global__ void zero_f(float* p, int n){
  int idx = blockIdx.x*256 + threadIdx.x;
  if (idx < n) p[idx] = 0.f;
}

// ---------------- attention window (per-batch block, 256 threads) ----------------
// computes p = h @ attn_W.T + attn_b, then Fx[8][LDF], Fy[8][LDF] into LDS; pl[0..4] = p
__device__ void attn_window(const float* __restrict__ h,
                            const float* __restrict__ attn_W,
                            const float* __restrict__ attn_b,
                            float* Fx, float* Fy, float* pl)
{
  int tid = threadIdx.x;
  int lane = tid & 63, wid = tid >> 6;
  for (int q = wid; q < 5; q += 4){
    float s = 0.f;
    for (int k = lane; k < 512; k += 64) s += h[k]*attn_W[q*512 + k];
    for (int m = 32; m; m >>= 1) s += __shfl_xor(s, m);
    if (lane == 0) pl[q] = s + attn_b[q];
  }
  __syncthreads();
  float gx    = 32.5f*(pl[0] + 1.f);
  float gy    = 32.5f*(pl[1] + 1.f);
  float s2    = __expf(pl[2]);
  float delta = 9.f*__expf(pl[3]);     // (64-1)*exp(log_d)/(8-1)
  float inv2  = 1.f/(2.f*s2);
  int n = tid >> 5, a = tid & 31;
  float mux = gx + ((float)n - 4.5f)*delta;
  float muy = gy + ((float)n - 4.5f)*delta;
  float dx0 = (float)a      - mux, dx1 = (float)(a+32) - mux;
  float dy0 = (float)a      - muy, dy1 = (float)(a+32) - muy;
  float e0 = __expf(-dx0*dx0*inv2), e1 = __expf(-dx1*dx1*inv2);
  float f0 = __expf(-dy0*dy0*inv2), f1 = __expf(-dy1*dy1*inv2);
  float sx = e0 + e1, sy = f0 + f1;
  for (int m = 16; m; m >>= 1){ sx += __shfl_xor(sx, m); sy += __shfl_xor(sy, m); }
  float rx = 1.f/(sx + EPSF), ry = 1.f/(sy + EPSF);
  Fx[n*LDF + a]      = e0*rx;  Fx[n*LDF + a + 32] = e1*rx;
  Fy[n*LDF + a]      = f0*ry;  Fy[n*LDF + a + 32] = f1*ry;
  __syncthreads();
}

// ---------------- glimpse kernel: attn(read) + read op -> r (512 x 128) ----------------
__global__ __launch_bounds__(256) void glimpse_kernel(
    const float* __restrict__ x, const float* __restrict__ canvas_prev,
    const float* __restrict__ h_dec,
    const float* __restrict__ attn_W, const float* __restrict__ attn_b,
    float* __restrict__ r_out)
{
  __shared__ float Fx[8*LDF], Fy[8*LDF];
  __shared__ float img_s[64*LDF], xh_s[64*LDF];
  __shared__ float P[2][8*LDF];
  __shared__ float pl[8];
  int b = blockIdx.x, tid = threadIdx.x;

  const float4* x4 = (const float4*)(x + (size_t)b*4096);
  const float4* c4 = canvas_prev ? (const float4*)(canvas_prev + (size_t)b*4096) : nullptr;
  for (int i = tid; i < 1024; i += 256){
    int row = i >> 4, cb = (i & 15) * 4;
    float4 xv = x4[i];
    float4 cv = c4 ? c4[i] : make_float4(0.f,0.f,0.f,0.f);
    *(float4*)&img_s[row*LDF + cb] = xv;
    float4 xh;
    xh.x = xv.x - sigf(cv.x); xh.y = xv.y - sigf(cv.y);
    xh.z = xv.z - sigf(cv.z); xh.w = xv.w - sigf(cv.w);
    *(float4*)&xh_s[row*LDF + cb] = xh;
  }
  attn_window(h_dec + (size_t)b*512, attn_W, attn_b, Fx, Fy, pl);
  // attn_window ends with __syncthreads(): img_s/xh_s/Fx/Fy all visible now
  float gamma = __expf(pl[4]);

  // P[im][m][h] = sum_w S_im[h][w] * Fx[m][w]
  #pragma unroll
  for (int e = 0; e < 4; e++){
    int gi  = e*256 + tid;
    int im  = gi >> 9, rem = gi & 511;
    int m   = rem & 7, hh = rem >> 3;
    const float* S = im ? xh_s : img_s;
    float s = 0.f;
    #pragma unroll
    for (int w4 = 0; w4 < 64; w4 += 4){
      float4 iv = *(const float4*)&S[hh*LDF + w4];
      float4 fv = *(const float4*)&Fx[m*LDF + w4];
      s += iv.x*fv.x + iv.y*fv.y + iv.z*fv.z + iv.w*fv.w;
    }
    P[im][m*LDF + hh] = s;
  }
  __syncthreads();

  // g[im][n][m] = sum_h Fy[n][h] * P[im][m][h];   r = g * gamma
  if (tid < 128){
    int im = tid >> 6, l = tid & 63;
    int n = l >> 3, m = l & 7;
    float s = 0.f;
    #pragma unroll
    for (int h4 = 0; h4 < 64; h4 += 4){
      float4 fv = *(const float4*)&Fy[n*LDF + h4];
      float4 pv = *(const float4*)&P[im][m*LDF + h4];
      s += fv.x*pv.x + fv.y*pv.y + fv.z*pv.z + fv.w*pv.w;
    }
    r_out[(size_t)b*128 + im*64 + n*8 + m] = s*gamma;
  }
}

// ---------------- GEMM (+ fused LSTM epilogue) ----------------
// g[m][n] = bias[n] + sum over up to 3 (A,W) pairs of A[m][:]·W[n][:]
// weights pre-reordered so cols 4j..4j+3 = gates (i,f,g,o) of unit j
__global__ __launch_bounds__(256) void gemm_lstm(
    const float* __restrict__ A0, const float* __restrict__ W0, int K0, int ldw0,
    const float* __restrict__ A1, const float* __restrict__ W1, int K1, int ldw1,
    const float* __restrict__ A2, const float* __restrict__ W2, int K2, int ldw2,
    const float* __restrict__ bias, const float* __restrict__ c_in,
    float* __restrict__ h_out, float* __restrict__ c_out)
{
  __shared__ float As[2][32*LDT];
  __shared__ float Ws[2][32*LDT];
  const int tid = threadIdx.x;
  const int tx = tid & 15, ty = tid >> 4;
  const int m0 = blockIdx.y * 64, n0 = blockIdx.x * 64;
  const int lr = tid >> 2;           // 0..63
  const int lc = (tid & 3) * 4;      // 0,4,8,12

  float acc[4][4];
  #pragma unroll
  for (int i = 0; i < 4; i++){
    #pragma unroll
    for (int j = 0; j < 4; j++) acc[i][j] = bias[n0 + tx*4 + j];
  }

  const int t0  = K0 >> 5;
  const int t01 = t0 + (K1 >> 5);
  const int nt  = t01 + (K2 >> 5);

  float4 ra0, ra1, rw0, rw1;

#define FETCH(TI) do { \
    const float* Ab; const float* Wb; int lda_, ldw_, ko_; \
    if ((TI) < t0)       { Ab = A0; Wb = W0; lda_ = K0; ldw_ = ldw0; ko_ = (TI)*32; } \
    else if ((TI) < t01) { Ab = A1; Wb = W1; lda_ = K1; ldw_ = ldw1; ko_ = ((TI)-t0)*32; } \
    else                 { Ab = A2; Wb = W2; lda_ = K2; ldw_ = ldw2; ko_ = ((TI)-t01)*32; } \
    const float* ap = Ab + (size_t)(m0+lr)*lda_ + ko_ + lc; \
    const float* wp = Wb + (size_t)(n0+lr)*ldw_ + ko_ + lc; \
    ra0 = *(const float4*)ap;       ra1 = *(const float4*)(ap + 16); \
    rw0 = *(const float4*)wp;       rw1 = *(const float4*)(wp + 16); \
  } while(0)

#define STORE(BUF) do { \
    float* as = &As[BUF][0]; float* wl = &Ws[BUF][0]; \
    as[(lc+ 0)*LDT+lr]=ra0.x; as[(lc+ 1)*LDT+lr]=ra0.y; as[(lc+ 2)*LDT+lr]=ra0.z; as[(lc+ 3)*LDT+lr]=ra0.w; \
    as[(lc+16)*LDT+lr]=ra1.x; as[(lc+17)*LDT+lr]=ra1.y; as[(lc+18)*LDT+lr]=ra1.z; as[(lc+19)*LDT+lr]=ra1.w; \
    wl[(lc+ 0)*LDT+lr]=rw0.x; wl[(lc+ 1)*LDT+lr]=rw0.y; wl[(lc+ 2)*LDT+lr]=rw0.z; wl[(lc+ 3)*LDT+lr]=rw0.w; \
    wl[(lc+16)*LDT+lr]=rw1.x; wl[(lc+17)*LDT+lr]=rw1.y; wl[(lc+18)*LDT+lr]=rw1.z; wl[(lc+19)*LDT+lr]=rw1.w; \
  } while(0)

  FETCH(0); STORE(0); __syncthreads();
  for (int ti = 0; ti < nt; ti++){
    int buf = ti & 1;
    if (ti + 1 < nt) FETCH(ti + 1);
    #pragma unroll
    for (int k = 0; k < 32; k++){
      float4 av = *(const float4*)&As[buf][k*LDT + ty*4];
      float4 wv = *(const float4*)&Ws[buf][k*LDT + tx*4];
      acc[0][0] += av.x*wv.x; acc[0][1] += av.x*wv.y; acc[0][2] += av.x*wv.z; acc[0][3] += av.x*wv.w;
      acc[1][0] += av.y*wv.x; acc[1][1] += av.y*wv.y; acc[1][2] += av.y*wv.z; acc[1][3] += av.y*wv.w;
      acc[2][0] += av.z*wv.x; acc[2][1] += av.z*wv.y; acc[2][2] += av.z*wv.z; acc[2][3] += av.z*wv.w;
      acc[3][0] += av.w*wv.x; acc[3][1] += av.w*wv.y; acc[3][2] += av.w*wv.z; acc[3][3] += av.w*wv.w;
    }
    __syncthreads();
    if (ti + 1 < nt) STORE(buf ^ 1);
    __syncthreads();
  }
#undef FETCH
#undef STORE

  // LSTM epilogue: acc[i][0..3] = (i,f,g,o) of unit ju for row m
  const int ju = (n0 >> 2) + tx;          // 0..511
  #pragma unroll
  for (int i = 0; i < 4; i++){
    int m = m0 + ty*4 + i;
    float ig = sigf(acc[i][0]);
    float fg = sigf(acc[i][1]);
    float gg = tanhf(acc[i][2]);
    float og = sigf(acc[i][3]);
    float c2 = fg * c_in[(size_t)m*512 + ju] + ig * gg;
    h_out[(size_t)m*512 + ju] = og * tanhf(c2);
    c_out[(size_t)m*512 + ju] = c2;
  }
}

// ---------------- z kernel: mu/sig GEMV + reparam ----------------
// block = 4 batch rows, 256 threads (n<128: mu unit n; n>=128: sig unit n-128)
__global__ __launch_bounds__(256) void z_kernel(
    const float* __restrict__ h_enc, const float* __restrict__ WzP,
    const float* __restrict__ mu_b, const float* __restrict__ sig_b,
    const float* __restrict__ eps_t, float* __restrict__ z_out)
{
  __shared__ float hs[4][512];
  __shared__ float sg[4][128];
  int b0 = blockIdx.x * 4, tid = threadIdx.x;
  for (int i = tid; i < 512; i += 256){
    int row = i >> 7, c = (i & 127) << 2;
    *(float4*)&hs[row][c] = *(const float4*)&h_enc[(size_t)(b0+row)*512 + c];
  }
  __syncthreads();
  float a0 = 0.f, a1 = 0.f, a2 = 0.f, a3 = 0.f;
  for (int kq = 0; kq < 128; kq++){
    float4 wv = *(const float4*)&WzP[kq*1024 + tid*4];
    float4 h0 = *(const float4*)&hs[0][kq*4];
    float4 h1 = *(const float4*)&hs[1][kq*4];
    float4 h2 = *(const float4*)&hs[2][kq*4];
    float4 h3 = *(const float4*)&hs[3][kq*4];
    a0 += h0.x*wv.x + h0.y*wv.y + h0.z*wv.z + h0.w*wv.w;
    a1 += h1.x*wv.x + h1.y*wv.y + h1.z*wv.z + h1.w*wv.w;
    a2 += h2.x*wv.x + h2.y*wv.y + h2.z*wv.z + h2.w*wv.w;
    a3 += h3.x*wv.x + h3.y*wv.y + h3.z*wv.z + h3.w*wv.w;
  }
  if (tid >= 128){
    int zn = tid - 128;
    float bb = sig_b[zn];
    sg[0][zn] = __expf(a0 + bb); sg[1][zn] = __expf(a1 + bb);
    sg[2][zn] = __expf(a2 + bb); sg[3][zn] = __expf(a3 + bb);
  }
  __syncthreads();
  if (tid < 128){
    int zn = tid;
    float bb = mu_b[zn];
    z_out[(size_t)(b0+0)*128 + zn] = a0 + bb + eps_t[(size_t)(b0+0)*128 + zn]*sg[0][zn];
    z_out[(size_t)(b0+1)*128 + zn] = a1 + bb + eps_t[(size_t)(b0+1)*128 + zn]*sg[1][zn];
    z_out[(size_t)(b0+2)*128 + zn] = a2 + bb + eps_t[(size_t)(b0+2)*128 + zn]*sg[2][zn];
    z_out[(size_t)(b0+3)*128 + zn] = a3 + bb + eps_t[(size_t)(b0+3)*128 + zn]*sg[3][zn];
  }
}

// ---------------- write kernel: w GEMV + attn(write) + canvas update ----------------
__global__ __launch_bounds__(256) void write_kernel(
    const float* __restrict__ h_dec, const float* __restrict__ WwT,
    const float* __restrict__ write_b,
    const float* __restrict__ attn_W, const float* __restrict__ attn_b,
    const float* __restrict__ canvas_prev, float* __restrict__ canvas_out)
{
  __shared__ float hs[512];
  __shared__ float Fx[8*LDF], Fy[8*LDF];
  __shared__ float pl[8];
  __shared__ float ps[4][64];
  __shared__ float w_s[64];
  __shared__ float tmp[64*8];
  int b = blockIdx.x, tid = threadIdx.x;

  for (int i = tid; i < 128; i += 256)
    ((float4*)hs)[i] = ((const float4*)(h_dec + (size_t)b*512))[i];
  __syncthreads();

  attn_window(hs, attn_W, attn_b, Fx, Fy, pl);

  // w[j] = write_b[j] + h · write_W[j]   (WwT is [k][j], coalesced)
  {
    int j = tid & 63, part = tid >> 6;
    float s = 0.f;
    int kb = part * 128;
    for (int k = 0; k < 128; k++) s += hs[kb + k] * WwT[(kb + k)*64 + j];
    ps[part][j] = s;
  }
  __syncthreads();
  if (tid < 64)
    w_s[tid] = write_b[tid] + ps[0][tid] + ps[1][tid] + ps[2][tid] + ps[3][tid];
  __syncthreads();

  float inv_g = __expf(-pl[4]);   // 1/gamma2

  // tmp[h][m] = sum_n Fy[n][h] * w[n][m]
  #pragma unroll
  for (int e = 0; e < 2; e++){
    int gi = e*256 + tid;
    int m = gi & 7, hh = gi >> 3;
    float s = 0.f;
    #pragma unroll
    for (int nn = 0; nn < 8; nn++) s += Fy[nn*LDF + hh] * w_s[nn*8 + m];
    tmp[hh*8 + m] = s;
  }
  __syncthreads();

  // canvas[h][a] += (sum_m tmp[h][m]*Fx[m][a]) / gamma
  for (int e = 0; e < 16; e++){
    int idx = e*256 + tid;
    int hh = idx >> 6, a = idx & 63;
    float s = 0.f;
    #pragma unroll
    for (int m = 0; m < 8; m++) s += tmp[hh*8 + m] * Fx[m*LDF + a];
    float prev = canvas_prev ? canvas_prev[(size_t)b*4096 + idx] : 0.f;
    canvas_out[(size_t)b*4096 + idx] = prev + s*inv_g;
  }
}

// ---------------- host launcher ----------------
extern "C" void kernel_launch(void* const* d_in, const int* in_sizes, int n_in,
                              void* d_out, int out_size, void* d_ws, size_t ws_size,
                              hipStream_t stream)
{
  (void)in_sizes; (void)n_in; (void)out_size; (void)ws_size;
  const float* x       = (const float*)d_in[0];
  const float* eps     = (const float*)d_in[1];
  const float* encWih  = (const float*)d_in[2];
  const float* encWhh  = (const float*)d_in[3];
  const float* enc_b   = (const float*)d_in[4];
  const float* muW     = (const float*)d_in[5];
  const float* mu_b    = (const float*)d_in[6];
  const float* sigW    = (const float*)d_in[7];
  const float* sig_b   = (const float*)d_in[8];
  const float* decWih  = (const float*)d_in[9];
  const float* decWhh  = (const float*)d_in[10];
  const float* dec_b   = (const float*)d_in[11];
  const float* writeW  = (const float*)d_in[12];
  const float* write_b = (const float*)d_in[13];
  const float* attnW   = (const float*)d_in[14];
  const float* attn_b  = (const float*)d_in[15];
  float* out = (float*)d_out;
  float* w   = (float*)d_ws;

  float* WihE = w;  w += 2048*640;
  float* WhhE = w;  w += 2048*512;
  float* WihD = w;  w += 2048*128;
  float* WhhD = w;  w += 2048*512;
  float* bE   = w;  w += 2048;
  float* bD   = w;  w += 2048;
  float* WzP  = w;  w += 512*256;
  float* WwT  = w;  w += 512*64;
  float* st   = w;  w += 8*512*512;
  float* rbuf = w;  w += 512*128;
  float* zbuf = w;  w += 512*128;
  float* hE[2] = { st + 0*262144, st + 1*262144 };
  float* cE[2] = { st + 2*262144, st + 3*262144 };
  float* hD[2] = { st + 4*262144, st + 5*262144 };
  float* cD[2] = { st + 6*262144, st + 7*262144 };

  int tot;
  tot = 2048*640; reorder_gates<<<(tot+255)/256,256,0,stream>>>(encWih, WihE, 512, 640, tot);
  tot = 2048*512; reorder_gates<<<(tot+255)/256,256,0,stream>>>(encWhh, WhhE, 512, 512, tot);
  tot = 2048*128; reorder_gates<<<(tot+255)/256,256,0,stream>>>(decWih, WihD, 512, 128, tot);
  tot = 2048*512; reorder_gates<<<(tot+255)/256,256,0,stream>>>(decWhh, WhhD, 512, 512, tot);
  tot = 2048;     reorder_gates<<<(tot+255)/256,256,0,stream>>>(enc_b,  bE,   512, 1,   tot);
  tot = 2048;     reorder_gates<<<(tot+255)/256,256,0,stream>>>(dec_b,  bD,   512, 1,   tot);
  tot = 512*256;  pack_wz<<<(tot+255)/256,256,0,stream>>>(muW, sigW, WzP);
  tot = 512*64;   transpose_ww<<<(tot+255)/256,256,0,stream>>>(writeW, WwT);
  tot = 8*262144; zero_f<<<(tot+255)/256,256,0,stream>>>(st, tot);

  for (int t = 0; t < 16; t++){
    int cur = t & 1, nxt = cur ^ 1;
    const float* cprev = t ? (out + (size_t)(t-1)*2097152) : nullptr;
    float* ccur = out + (size_t)t*2097152;

    glimpse_kernel<<<512,256,0,stream>>>(x, cprev, hD[cur], attnW, attn_b, rbuf);

    gemm_lstm<<<dim3(32,8),256,0,stream>>>(rbuf,   WihE,       128, 640,
                                           hD[cur], WihE + 128, 512, 640,
                                           hE[cur], WhhE,       512, 512,
                                           bE, cE[cur], hE[nxt], cE[nxt]);

    z_kernel<<<128,256,0,stream>>>(hE[nxt], WzP, mu_b, sig_b,
                                   eps + (size_t)t*65536, zbuf);

    gemm_lstm<<<dim3(32,8),256,0,stream>>>(zbuf,   WihD, 128, 128,
                                           hD[cur], WhhD, 512, 512,
                                           nullptr, nullptr, 0, 0,
                                           bD, cD[cur], hD[nxt], cD[nxt]);

    write_kernel<<<512,256,0,stream>>>(hD[nxt], WwT, write_b, attnW, attn_b,
                                       cprev, ccur);
  }
}

// Round 3
// 1887.165 us; speedup vs baseline: 1.2192x; 1.2192x over previous
//
#include <hip/hip_runtime.h>

#define LDF 68
#define EPSF 1e-8f

typedef __attribute__((ext_vector_type(8))) short bf16x8;
typedef __attribute__((ext_vector_type(4))) float f32x4;

__device__ __forceinline__ float sigf(float x){ return 1.0f/(1.0f + __expf(-x)); }

__device__ __forceinline__ unsigned short f2bf(float f){
  unsigned u = __float_as_uint(f);
  u += 0x7FFFu + ((u >> 16) & 1u);
  return (unsigned short)(u >> 16);
}
__device__ __forceinline__ float bf2f(unsigned short s){
  return __uint_as_float((unsigned)s << 16);
}

// ---------------- init kernels ----------------
__global__ void reorder_gates(const float* __restrict__ src, float* __restrict__ dst,
                              int H, int K, int total){
  int idx = blockIdx.x*256 + threadIdx.x;
  if (idx >= total) return;
  int row = idx / K;
  int col = idx - row*K;
  int j = row >> 2, g = row & 3;
  dst[idx] = src[(size_t)(g*H + j)*K + col];
}

// pack gate-reordered [2048 x K_tot] weights (f32 src: Wih | Whh) into bf16 hi+lo MFMA frags
// dst[((fm*KB + kb)*64 + lane)*8 + i] = W[fm*16 + (lane&15)][kb*32 + (lane>>4)*8 + i]
__global__ void pack_w_mfma(const float* __restrict__ Wih, const float* __restrict__ Whh,
                            int K_ih, int K_tot,
                            unsigned short* __restrict__ dhi, unsigned short* __restrict__ dlo,
                            int total8){
  int idx = blockIdx.x*256 + threadIdx.x;
  if (idx >= total8) return;
  int lane = idx & 63;
  int rest = idx >> 6;
  int KB = K_tot >> 5;
  int kb = rest % KB;
  int fm = rest / KB;
  int rr = fm*16 + (lane & 15);
  int orow = (rr & 3)*512 + (rr >> 2);     // gate-reorder fused
  int k0 = kb*32 + (lane >> 4)*8;
  union { unsigned short s[8]; uint4 u; } vh, vl;
  #pragma unroll
  for (int i = 0; i < 8; i++){
    int k = k0 + i;
    float f = (k < K_ih) ? Wih[(size_t)orow*K_ih + k]
                         : Whh[(size_t)orow*512 + (k - K_ih)];
    unsigned short hi = f2bf(f);
    vh.s[i] = hi;
    vl.s[i] = f2bf(f - bf2f(hi));
  }
  *(uint4*)(dhi + (size_t)idx*8) = vh.u;
  *(uint4*)(dlo + (size_t)idx*8) = vl.u;
}

// WzP[(k>>2)*1024 + n*4 + (k&3)] = n<128 ? muW[n][k] : sigW[n-128][k]
__global__ void pack_wz(const float* __restrict__ muW, const float* __restrict__ sigW,
                        float* __restrict__ dst){
  int idx = blockIdx.x*256 + threadIdx.x;
  if (idx >= 512*256) return;
  int k = idx >> 8, n = idx & 255;
  float v = (n < 128) ? muW[n*512 + k] : sigW[(n-128)*512 + k];
  dst[(k>>2)*1024 + n*4 + (k&3)] = v;
}

__global__ void transpose_ww(const float* __restrict__ W, float* __restrict__ dst){
  int idx = blockIdx.x*256 + threadIdx.x;
  if (idx >= 512*64) return;
  int k = idx >> 6, n = idx & 63;
  dst[idx] = W[n*512 + k];
}

__global__ void zero_f(float* p, int n){
  int idx = blockIdx.x*256 + threadIdx.x;
  if (idx < n) p[idx] = 0.f;
}

// ---------------- attention window helper ----------------
__device__ void attn_window(const float* __restrict__ h,
                            const float* __restrict__ attn_W,
                            const float* __restrict__ attn_b,
                            float* Fx, float* Fy, float* pl)
{
  int tid = threadIdx.x;
  int lane = tid & 63, wid = tid >> 6;
  for (int q = wid; q < 5; q += 4){
    float s = 0.f;
    for (int k = lane; k < 512; k += 64) s += h[k]*attn_W[q*512 + k];
    for (int m = 32; m; m >>= 1) s += __shfl_xor(s, m);
    if (lane == 0) pl[q] = s + attn_b[q];
  }
  __syncthreads();
  float gx    = 32.5f*(pl[0] + 1.f);
  float gy    = 32.5f*(pl[1] + 1.f);
  float s2    = __expf(pl[2]);
  float delta = 9.f*__expf(pl[3]);
  float inv2  = 1.f/(2.f*s2);
  int n = tid >> 5, a = tid & 31;
  float mux = gx + ((float)n - 4.5f)*delta;
  float muy = gy + ((float)n - 4.5f)*delta;
  float dx0 = (float)a      - mux, dx1 = (float)(a+32) - mux;
  float dy0 = (float)a      - muy, dy1 = (float)(a+32) - muy;
  float e0 = __expf(-dx0*dx0*inv2), e1 = __expf(-dx1*dx1*inv2);
  float f0 = __expf(-dy0*dy0*inv2), f1 = __expf(-dy1*dy1*inv2);
  float sx = e0 + e1, sy = f0 + f1;
  for (int m = 16; m; m >>= 1){ sx += __shfl_xor(sx, m); sy += __shfl_xor(sy, m); }
  float rx = 1.f/(sx + EPSF), ry = 1.f/(sy + EPSF);
  Fx[n*LDF + a]      = e0*rx;  Fx[n*LDF + a + 32] = e1*rx;
  Fy[n*LDF + a]      = f0*ry;  Fy[n*LDF + a + 32] = f1*ry;
  __syncthreads();
}

// ---------------- glimpse: attn(read) + read op -> bf16 hi/lo r slice of actE ----------------
__global__ __launch_bounds__(256) void glimpse_kernel(
    const float* __restrict__ x, const float* __restrict__ canvas_prev,
    const float* __restrict__ h_dec,
    const float* __restrict__ attn_W, const float* __restrict__ attn_b,
    unsigned short* __restrict__ actE, int planeE)
{
  __shared__ float Fx[8*LDF], Fy[8*LDF];
  __shared__ float img_s[64*LDF], xh_s[64*LDF];
  __shared__ float P[2][8*LDF];
  __shared__ float pl[8];
  int b = blockIdx.x, tid = threadIdx.x;

  const float4* x4 = (const float4*)(x + (size_t)b*4096);
  const float4* c4 = canvas_prev ? (const float4*)(canvas_prev + (size_t)b*4096) : nullptr;
  for (int i = tid; i < 1024; i += 256){
    int row = i >> 4, cb = (i & 15) * 4;
    float4 xv = x4[i];
    float4 cv = c4 ? c4[i] : make_float4(0.f,0.f,0.f,0.f);
    *(float4*)&img_s[row*LDF + cb] = xv;
    float4 xh;
    xh.x = xv.x - sigf(cv.x); xh.y = xv.y - sigf(cv.y);
    xh.z = xv.z - sigf(cv.z); xh.w = xv.w - sigf(cv.w);
    *(float4*)&xh_s[row*LDF + cb] = xh;
  }
  attn_window(h_dec + (size_t)b*512, attn_W, attn_b, Fx, Fy, pl);
  float gamma = __expf(pl[4]);

  #pragma unroll
  for (int e = 0; e < 4; e++){
    int gi  = e*256 + tid;
    int im  = gi >> 9, rem = gi & 511;
    int m   = rem & 7, hh = rem >> 3;
    const float* S = im ? xh_s : img_s;
    float s = 0.f;
    #pragma unroll
    for (int w4 = 0; w4 < 64; w4 += 4){
      float4 iv = *(const float4*)&S[hh*LDF + w4];
      float4 fv = *(const float4*)&Fx[m*LDF + w4];
      s += iv.x*fv.x + iv.y*fv.y + iv.z*fv.z + iv.w*fv.w;
    }
    P[im][m*LDF + hh] = s;
  }
  __syncthreads();

  if (tid < 128){
    int im = tid >> 6, l = tid & 63;
    int n = l >> 3, m = l & 7;
    float s = 0.f;
    #pragma unroll
    for (int h4 = 0; h4 < 64; h4 += 4){
      float4 fv = *(const float4*)&Fy[n*LDF + h4];
      float4 pv = *(const float4*)&P[im][m*LDF + h4];
      s += fv.x*pv.x + fv.y*pv.y + fv.z*pv.z + fv.w*pv.w;
    }
    float r = s*gamma;
    unsigned short hi = f2bf(r);
    size_t o = (size_t)b*1152 + im*64 + n*8 + m;
    actE[o] = hi;
    actE[o + planeE] = f2bf(r - bf2f(hi));
  }
}

// ---------------- MFMA GEMM (split hi/lo) + fused LSTM epilogue ----------------
// D[2048 unit-gate rows][512 batch cols] = (Wh+Wl) · (Ah+Al)^T, 3-term expansion
__global__ __launch_bounds__(256) void mfma_gemm_lstm(
    const bf16x8* __restrict__ Wh, const bf16x8* __restrict__ Wl,
    const unsigned short* __restrict__ act, int K, int actPlane,
    const float4* __restrict__ bias4, const float* __restrict__ c_in,
    float* __restrict__ h_f32, float* __restrict__ c_out,
    unsigned short* __restrict__ hb0, int str0, int off0, int pl0,
    unsigned short* __restrict__ hb1, int str1, int off1, int pl1)
{
  int bid = blockIdx.x;
  int mt = bid & 31, nt = bid >> 5;
  int tid = threadIdx.x, lane = tid & 63, w = tid >> 6;
  int wm = w >> 1, wn = w & 1;
  int KB = K >> 5;

  int fm0 = mt*4 + wm*2;
  int b00 = nt*64 + wn*32 + (lane & 15);
  int koff = (lane >> 4) * 8;

  const bf16x8* wh0 = Wh + ((size_t)fm0     * KB)*64 + lane;
  const bf16x8* wh1 = Wh + ((size_t)(fm0+1) * KB)*64 + lane;
  const bf16x8* wl0 = Wl + ((size_t)fm0     * KB)*64 + lane;
  const bf16x8* wl1 = Wl + ((size_t)(fm0+1) * KB)*64 + lane;
  const unsigned short* ab0 = act + (size_t)b00*K + koff;
  const unsigned short* ab1 = act + (size_t)(b00+16)*K + koff;

  int j0 = fm0*4 + (lane >> 4);
  float4 bb0 = bias4[j0], bb1 = bias4[j0+4];
  f32x4 acc00 = {bb0.x,bb0.y,bb0.z,bb0.w};
  f32x4 acc01 = acc00;
  f32x4 acc10 = {bb1.x,bb1.y,bb1.z,bb1.w};
  f32x4 acc11 = acc10;

  #pragma unroll 2
  for (int kb = 0; kb < KB; kb++){
    bf16x8 a0h = wh0[kb*64];
    bf16x8 a1h = wh1[kb*64];
    bf16x8 a0l = wl0[kb*64];
    bf16x8 a1l = wl1[kb*64];
    bf16x8 b0h = *(const bf16x8*)(ab0 + kb*32);
    bf16x8 b1h = *(const bf16x8*)(ab1 + kb*32);
    bf16x8 b0l = *(const bf16x8*)(ab0 + actPlane + kb*32);
    bf16x8 b1l = *(const bf16x8*)(ab1 + actPlane + kb*32);
    acc00 = __builtin_amdgcn_mfma_f32_16x16x32_bf16(a0h, b0h, acc00, 0, 0, 0);
    acc01 = __builtin_amdgcn_mfma_f32_16x16x32_bf16(a0h, b1h, acc01, 0, 0, 0);
    acc10 = __builtin_amdgcn_mfma_f32_16x16x32_bf16(a1h, b0h, acc10, 0, 0, 0);
    acc11 = __builtin_amdgcn_mfma_f32_16x16x32_bf16(a1h, b1h, acc11, 0, 0, 0);
    acc00 = __builtin_amdgcn_mfma_f32_16x16x32_bf16(a0l, b0h, acc00, 0, 0, 0);
    acc01 = __builtin_amdgcn_mfma_f32_16x16x32_bf16(a0l, b1h, acc01, 0, 0, 0);
    acc10 = __builtin_amdgcn_mfma_f32_16x16x32_bf16(a1l, b0h, acc10, 0, 0, 0);
    acc11 = __builtin_amdgcn_mfma_f32_16x16x32_bf16(a1l, b1h, acc11, 0, 0, 0);
    acc00 = __builtin_amdgcn_mfma_f32_16x16x32_bf16(a0h, b0l, acc00, 0, 0, 0);
    acc01 = __builtin_amdgcn_mfma_f32_16x16x32_bf16(a0h, b1l, acc01, 0, 0, 0);
    acc10 = __builtin_amdgcn_mfma_f32_16x16x32_bf16(a1h, b0l, acc10, 0, 0, 0);
    acc11 = __builtin_amdgcn_mfma_f32_16x16x32_bf16(a1h, b1l, acc11, 0, 0, 0);
  }

  #pragma unroll
  for (int mi = 0; mi < 2; mi++){
    #pragma unroll
    for (int ni = 0; ni < 2; ni++){
      f32x4 g = (mi==0) ? (ni==0 ? acc00 : acc01) : (ni==0 ? acc10 : acc11);
      int j = j0 + mi*4;
      int b = b00 + ni*16;
      float ig = sigf(g[0]);
      float fg = sigf(g[1]);
      float gg = tanhf(g[2]);
      float og = sigf(g[3]);
      float c2 = fg * c_in[(size_t)b*512 + j] + ig * gg;
      float h  = og * tanhf(c2);
      h_f32[(size_t)b*512 + j] = h;
      c_out[(size_t)b*512 + j] = c2;
      unsigned short hbh = f2bf(h);
      unsigned short hbl = f2bf(h - bf2f(hbh));
      size_t o0 = (size_t)b*str0 + off0 + j;
      hb0[o0] = hbh; hb0[o0 + pl0] = hbl;
      if (hb1){
        size_t o1 = (size_t)b*str1 + off1 + j;
        hb1[o1] = hbh; hb1[o1 + pl1] = hbl;
      }
    }
  }
}

// ---------------- z kernel: mu/sig GEMV + reparam -> bf16 hi/lo z slice of actD ----------------
__global__ __launch_bounds__(256) void z_kernel(
    const float* __restrict__ h_enc, const float* __restrict__ WzP,
    const float* __restrict__ mu_b, const float* __restrict__ sig_b,
    const float* __restrict__ eps_t, unsigned short* __restrict__ actD, int planeD)
{
  __shared__ float hs[4][512];
  __shared__ float sg[4][128];
  int b0 = blockIdx.x * 4, tid = threadIdx.x;
  for (int i = tid; i < 512; i += 256){
    int row = i >> 7, c = (i & 127) << 2;
    *(float4*)&hs[row][c] = *(const float4*)&h_enc[(size_t)(b0+row)*512 + c];
  }
  __syncthreads();
  float a0 = 0.f, a1 = 0.f, a2 = 0.f, a3 = 0.f;
  for (int kq = 0; kq < 128; kq++){
    float4 wv = *(const float4*)&WzP[kq*1024 + tid*4];
    float4 h0 = *(const float4*)&hs[0][kq*4];
    float4 h1 = *(const float4*)&hs[1][kq*4];
    float4 h2 = *(const float4*)&hs[2][kq*4];
    float4 h3 = *(const float4*)&hs[3][kq*4];
    a0 += h0.x*wv.x + h0.y*wv.y + h0.z*wv.z + h0.w*wv.w;
    a1 += h1.x*wv.x + h1.y*wv.y + h1.z*wv.z + h1.w*wv.w;
    a2 += h2.x*wv.x + h2.y*wv.y + h2.z*wv.z + h2.w*wv.w;
    a3 += h3.x*wv.x + h3.y*wv.y + h3.z*wv.z + h3.w*wv.w;
  }
  if (tid >= 128){
    int zn = tid - 128;
    float bb = sig_b[zn];
    sg[0][zn] = __expf(a0 + bb); sg[1][zn] = __expf(a1 + bb);
    sg[2][zn] = __expf(a2 + bb); sg[3][zn] = __expf(a3 + bb);
  }
  __syncthreads();
  if (tid < 128){
    int zn = tid;
    float bb = mu_b[zn];
    #pragma unroll
    for (int r = 0; r < 4; r++){
      float a = (r==0?a0:r==1?a1:r==2?a2:a3);
      float z = a + bb + eps_t[(size_t)(b0+r)*128 + zn]*sg[r][zn];
      unsigned short hi = f2bf(z);
      size_t o = (size_t)(b0+r)*640 + zn;
      actD[o] = hi;
      actD[o + planeD] = f2bf(z - bf2f(hi));
    }
  }
}

// ---------------- write kernel ----------------
__global__ __launch_bounds__(256) void write_kernel(
    const float* __restrict__ h_dec, const float* __restrict__ WwT,
    const float* __restrict__ write_b,
    const float* __restrict__ attn_W, const float* __restrict__ attn_b,
    const float* __restrict__ canvas_prev, float* __restrict__ canvas_out)
{
  __shared__ float hs[512];
  __shared__ float Fx[8*LDF], Fy[8*LDF];
  __shared__ float pl[8];
  __shared__ float ps[4][64];
  __shared__ float w_s[64];
  __shared__ float tmp[64*8];
  int b = blockIdx.x, tid = threadIdx.x;

  for (int i = tid; i < 128; i += 256)
    ((float4*)hs)[i] = ((const float4*)(h_dec + (size_t)b*512))[i];
  __syncthreads();

  attn_window(hs, attn_W, attn_b, Fx, Fy, pl);

  {
    int j = tid & 63, part = tid >> 6;
    float s = 0.f;
    int kb = part * 128;
    for (int k = 0; k < 128; k++) s += hs[kb + k] * WwT[(kb + k)*64 + j];
    ps[part][j] = s;
  }
  __syncthreads();
  if (tid < 64)
    w_s[tid] = write_b[tid] + ps[0][tid] + ps[1][tid] + ps[2][tid] + ps[3][tid];
  __syncthreads();

  float inv_g = __expf(-pl[4]);

  #pragma unroll
  for (int e = 0; e < 2; e++){
    int gi = e*256 + tid;
    int m = gi & 7, hh = gi >> 3;
    float s = 0.f;
    #pragma unroll
    for (int nn = 0; nn < 8; nn++) s += Fy[nn*LDF + hh] * w_s[nn*8 + m];
    tmp[hh*8 + m] = s;
  }
  __syncthreads();

  for (int e = 0; e < 16; e++){
    int idx = e*256 + tid;
    int hh = idx >> 6, a = idx & 63;
    float s = 0.f;
    #pragma unroll
    for (int m = 0; m < 8; m++) s += tmp[hh*8 + m] * Fx[m*LDF + a];
    float prev = canvas_prev ? canvas_prev[(size_t)b*4096 + idx] : 0.f;
    canvas_out[(size_t)b*4096 + idx] = prev + s*inv_g;
  }
}

// ---------------- host launcher ----------------
extern "C" void kernel_launch(void* const* d_in, const int* in_sizes, int n_in,
                              void* d_out, int out_size, void* d_ws, size_t ws_size,
                              hipStream_t stream)
{
  (void)in_sizes; (void)n_in; (void)out_size; (void)ws_size;
  const float* x       = (const float*)d_in[0];
  const float* eps     = (const float*)d_in[1];
  const float* encWih  = (const float*)d_in[2];
  const float* encWhh  = (const float*)d_in[3];
  const float* enc_b   = (const float*)d_in[4];
  const float* muW     = (const float*)d_in[5];
  const float* mu_b    = (const float*)d_in[6];
  const float* sigW    = (const float*)d_in[7];
  const float* sig_b   = (const float*)d_in[8];
  const float* decWih  = (const float*)d_in[9];
  const float* decWhh  = (const float*)d_in[10];
  const float* dec_b   = (const float*)d_in[11];
  const float* writeW  = (const float*)d_in[12];
  const float* write_b = (const float*)d_in[13];
  const float* attnW   = (const float*)d_in[14];
  const float* attn_b  = (const float*)d_in[15];
  float* out = (float*)d_out;

  char* p = (char*)d_ws;
  auto alloc = [&](size_t bytes){ char* r = p; p += (bytes + 255) & ~(size_t)255; return r; };

  const int KE = 1152, KD = 640;
  const int PE = 512*KE, PD = 512*KD;       // act plane sizes (elements)
  const int T8E = 128*(KE/32)*64;
  const int T8D = 128*(KD/32)*64;

  unsigned short* WpEh = (unsigned short*)alloc((size_t)T8E*16);
  unsigned short* WpEl = (unsigned short*)alloc((size_t)T8E*16);
  unsigned short* WpDh = (unsigned short*)alloc((size_t)T8D*16);
  unsigned short* WpDl = (unsigned short*)alloc((size_t)T8D*16);
  float* bE  = (float*)alloc(2048*4);
  float* bD  = (float*)alloc(2048*4);
  float* WzP = (float*)alloc(512*256*4);
  float* WwT = (float*)alloc(512*64*4);
  float* hEf = (float*)alloc(512*512*4);
  // contiguous zero-init region: actE[0](hi+lo), actD[0](hi+lo), hD0, cE0, cD0
  char* z0 = p;
  unsigned short* actE0 = (unsigned short*)alloc((size_t)2*PE*2);
  unsigned short* actD0 = (unsigned short*)alloc((size_t)2*PD*2);
  float* hD0 = (float*)alloc(512*512*4);
  float* cE0 = (float*)alloc(512*512*4);
  float* cD0 = (float*)alloc(512*512*4);
  size_t zbytes = (size_t)(p - z0);
  unsigned short* actE1 = (unsigned short*)alloc((size_t)2*PE*2);
  unsigned short* actD1 = (unsigned short*)alloc((size_t)2*PD*2);
  float* hD1 = (float*)alloc(512*512*4);
  float* cE1 = (float*)alloc(512*512*4);
  float* cD1 = (float*)alloc(512*512*4);

  unsigned short* actE[2] = { actE0, actE1 };
  unsigned short* actD[2] = { actD0, actD1 };
  float* hDf[2] = { hD0, hD1 };
  float* cEf[2] = { cE0, cE1 };
  float* cDf[2] = { cD0, cD1 };

  int tot;
  tot = T8E;      pack_w_mfma<<<(tot+255)/256,256,0,stream>>>(encWih, encWhh, 640, KE, WpEh, WpEl, tot);
  tot = T8D;      pack_w_mfma<<<(tot+255)/256,256,0,stream>>>(decWih, decWhh, 128, KD, WpDh, WpDl, tot);
  tot = 2048;     reorder_gates<<<(tot+255)/256,256,0,stream>>>(enc_b, bE, 512, 1, tot);
  tot = 2048;     reorder_gates<<<(tot+255)/256,256,0,stream>>>(dec_b, bD, 512, 1, tot);
  tot = 512*256;  pack_wz<<<(tot+255)/256,256,0,stream>>>(muW, sigW, WzP);
  tot = 512*64;   transpose_ww<<<(tot+255)/256,256,0,stream>>>(writeW, WwT);
  tot = (int)(zbytes/4); zero_f<<<(tot+255)/256,256,0,stream>>>((float*)z0, tot);

  for (int t = 0; t < 16; t++){
    int cur = t & 1, nxt = cur ^ 1;
    const float* cprev = t ? (out + (size_t)(t-1)*2097152) : nullptr;
    float* ccur = out + (size_t)t*2097152;

    glimpse_kernel<<<512,256,0,stream>>>(x, cprev, hDf[cur], attnW, attn_b,
                                         actE[cur], PE);

    mfma_gemm_lstm<<<256,256,0,stream>>>((const bf16x8*)WpEh, (const bf16x8*)WpEl,
                                         actE[cur], KE, PE,
                                         (const float4*)bE, cEf[cur],
                                         hEf, cEf[nxt],
                                         actE[nxt], KE, 640, PE,
                                         nullptr, 0, 0, 0);

    z_kernel<<<128,256,0,stream>>>(hEf, WzP, mu_b, sig_b,
                                   eps + (size_t)t*65536, actD[cur], PD);

    mfma_gemm_lstm<<<256,256,0,stream>>>((const bf16x8*)WpDh, (const bf16x8*)WpDl,
                                         actD[cur], KD, PD,
                                         (const float4*)bD, cDf[cur],
                                         hDf[nxt], cDf[nxt],
                                         actE[nxt], KE, 128, PE,
                                         actD[nxt], KD, 128, PD);

    write_kernel<<<512,256,0,stream>>>(hDf[nxt], WwT, write_b, attnW, attn_b,
                                       cprev, ccur);
  }
}

// Round 5
// 1091.572 us; speedup vs baseline: 2.1079x; 1.7289x over previous
//
#include <hip/hip_runtime.h>

#define LDF 68
#define EPSF 1e-8f
#define MFMA(A,B,C) __builtin_amdgcn_mfma_f32_16x16x32_bf16((A),(B),(C),0,0,0)

typedef __attribute__((ext_vector_type(8))) short bf16x8;
typedef __attribute__((ext_vector_type(4))) float f32x4;

__device__ __forceinline__ float sigf(float x){ return 1.0f/(1.0f + __expf(-x)); }

__device__ __forceinline__ unsigned short f2bf(float f){
  unsigned u = __float_as_uint(f);
  u += 0x7FFFu + ((u >> 16) & 1u);
  return (unsigned short)(u >> 16);
}
__device__ __forceinline__ float bf2f(unsigned short s){
  return __uint_as_float((unsigned)s << 16);
}

// packed-activation element index (u16 units) within one plane
__device__ __forceinline__ size_t pk(int b, int col, int KB){
  return ((((size_t)((b>>4)*KB + (col>>5)))*64) + (size_t)((b&15) + (((col>>3)&3)<<4)))*8 + (col&7);
}

__device__ __forceinline__ void gload_lds16(const void* g, void* l){
  __builtin_amdgcn_global_load_lds(
      (const __attribute__((address_space(1))) void*)g,
      (__attribute__((address_space(3))) void*)l, 16, 0, 0);
}

// ---------------- init kernels ----------------
__global__ void reorder_gates(const float* __restrict__ src, float* __restrict__ dst,
                              int H, int K, int total){
  int idx = blockIdx.x*256 + threadIdx.x;
  if (idx >= total) return;
  int row = idx / K;
  int col = idx - row*K;
  int j = row >> 2, g = row & 3;
  dst[idx] = src[(size_t)(g*H + j)*K + col];
}

// pack gate-reordered [2048 x K_tot] weights (f32: Wih|Whh) into bf16 hi+lo MFMA frags
__global__ void pack_w_mfma(const float* __restrict__ Wih, const float* __restrict__ Whh,
                            int K_ih, int K_tot,
                            unsigned short* __restrict__ dhi, unsigned short* __restrict__ dlo,
                            int total8){
  int idx = blockIdx.x*256 + threadIdx.x;
  if (idx >= total8) return;
  int lane = idx & 63;
  int rest = idx >> 6;
  int KB = K_tot >> 5;
  int kb = rest % KB;
  int fm = rest / KB;
  int rr = fm*16 + (lane & 15);
  int orow = (rr & 3)*512 + (rr >> 2);     // gate reorder fused
  int k0 = kb*32 + (lane >> 4)*8;
  union { unsigned short s[8]; uint4 u; } vh, vl;
  #pragma unroll
  for (int i = 0; i < 8; i++){
    int k = k0 + i;
    float f = (k < K_ih) ? Wih[(size_t)orow*K_ih + k]
                         : Whh[(size_t)orow*512 + (k - K_ih)];
    unsigned short hi = f2bf(f);
    vh.s[i] = hi;
    vl.s[i] = f2bf(f - bf2f(hi));
  }
  *(uint4*)(dhi + (size_t)idx*8) = vh.u;
  *(uint4*)(dlo + (size_t)idx*8) = vl.u;
}

// pack [mu_W;sig_W] (256x512) into bf16 hi+lo frags, no gate reorder
__global__ void pack_wz_mfma(const float* __restrict__ muW, const float* __restrict__ sigW,
                             unsigned short* __restrict__ dhi, unsigned short* __restrict__ dlo){
  int idx = blockIdx.x*256 + threadIdx.x;
  if (idx >= 16384) return;
  int lane = idx & 63, rest = idx >> 6;
  int kb = rest & 15, fmf = rest >> 4;
  int row = fmf*16 + (lane & 15);
  const float* src = (row < 128) ? (muW + (size_t)row*512) : (sigW + (size_t)(row-128)*512);
  int k0 = kb*32 + (lane >> 4)*8;
  union { unsigned short s[8]; uint4 u; } vh, vl;
  #pragma unroll
  for (int i = 0; i < 8; i++){
    float f = src[k0 + i];
    unsigned short hi = f2bf(f);
    vh.s[i] = hi;
    vl.s[i] = f2bf(f - bf2f(hi));
  }
  *(uint4*)(dhi + (size_t)idx*8) = vh.u;
  *(uint4*)(dlo + (size_t)idx*8) = vl.u;
}

__global__ void transpose_ww(const float* __restrict__ W, float* __restrict__ dst){
  int idx = blockIdx.x*256 + threadIdx.x;
  if (idx >= 512*64) return;
  int k = idx >> 6, n = idx & 63;
  dst[idx] = W[n*512 + k];
}

__global__ void zero_f(float* p, int n){
  int idx = blockIdx.x*256 + threadIdx.x;
  if (idx < n) p[idx] = 0.f;
}

// ---------------- attention window helper ----------------
__device__ void attn_window(const float* __restrict__ h,
                            const float* __restrict__ attn_W,
                            const float* __restrict__ attn_b,
                            float* Fx, float* Fy, float* pl)
{
  int tid = threadIdx.x;
  int lane = tid & 63, wid = tid >> 6;
  for (int q = wid; q < 5; q += 4){
    float s = 0.f;
    for (int k = lane; k < 512; k += 64) s += h[k]*attn_W[q*512 + k];
    for (int m = 32; m; m >>= 1) s += __shfl_xor(s, m);
    if (lane == 0) pl[q] = s + attn_b[q];
  }
  __syncthreads();
  float gx    = 32.5f*(pl[0] + 1.f);
  float gy    = 32.5f*(pl[1] + 1.f);
  float s2    = __expf(pl[2]);
  float delta = 9.f*__expf(pl[3]);
  float inv2  = 1.f/(2.f*s2);
  int n = tid >> 5, a = tid & 31;
  float mux = gx + ((float)n - 4.5f)*delta;
  float muy = gy + ((float)n - 4.5f)*delta;
  float dx0 = (float)a      - mux, dx1 = (float)(a+32) - mux;
  float dy0 = (float)a      - muy, dy1 = (float)(a+32) - muy;
  float e0 = __expf(-dx0*dx0*inv2), e1 = __expf(-dx1*dx1*inv2);
  float f0 = __expf(-dy0*dy0*inv2), f1 = __expf(-dy1*dy1*inv2);
  float sx = e0 + e1, sy = f0 + f1;
  for (int m = 16; m; m >>= 1){ sx += __shfl_xor(sx, m); sy += __shfl_xor(sy, m); }
  float rx = 1.f/(sx + EPSF), ry = 1.f/(sy + EPSF);
  Fx[n*LDF + a]      = e0*rx;  Fx[n*LDF + a + 32] = e1*rx;
  Fy[n*LDF + a]      = f0*ry;  Fy[n*LDF + a + 32] = f1*ry;
  __syncthreads();
}

// ---------------- MFMA GEMM (split hi/lo) + fused LSTM epilogue ----------------
// 64x64 tile, 8 waves; acts LDS-staged (dbuf) via global_load_lds; weights reg-direct.
template<int KB>
__global__ __launch_bounds__(512) void mfma_gemm_lstm(
    const bf16x8* __restrict__ Wh, const bf16x8* __restrict__ Wl,
    const unsigned short* __restrict__ act, int actPlane,
    const float4* __restrict__ bias4, const float* __restrict__ c_in,
    float* __restrict__ h_f32, float* __restrict__ c_out,
    unsigned short* __restrict__ out0, int KB0, int off0, int plane0,
    unsigned short* __restrict__ out1, int KB1, int off1, int plane1)
{
  __shared__ __align__(16) unsigned char lds[2][8192];
  const int tid = threadIdx.x, lane = tid & 63, w = tid >> 6;
  const int mt = blockIdx.x & 31, nt = blockIdx.x >> 5;
  const int fm = w & 3, fn0 = (w >> 2) << 1;

  const bf16x8* whp = Wh + ((size_t)(mt*4+fm)*KB)*64 + lane;
  const bf16x8* wlp = Wl + ((size_t)(mt*4+fm)*KB)*64 + lane;

  // this wave stages chunk (fn = w>>1, plane = w&1), 1 KB per kb
  const char* ast = (const char*)act + (size_t)(w & 1)*((size_t)actPlane*2)
                  + ((size_t)(nt*4 + (w >> 1))*KB)*1024 + (size_t)lane*16;
  char* myl0 = (char*)&lds[0][w*1024];
  char* myl1 = (char*)&lds[1][w*1024];

  const int j0 = (mt*4+fm)*4 + (lane >> 4);   // unit id
  float4 bb = bias4[j0];
  f32x4 acc0 = {bb.x, bb.y, bb.z, bb.w};
  f32x4 acc1 = acc0;

  gload_lds16(ast, myl0);
  asm volatile("s_waitcnt vmcnt(0)");
  __syncthreads();

  const unsigned char* rb0 = &lds[0][fn0*2048];
  const unsigned char* rb1 = &lds[1][fn0*2048];

  bf16x8 whv = whp[0];
  bf16x8 wlv = wlp[0];

  for (int kb = 0; kb < KB; kb++){
    int cur = kb & 1;
    if (kb + 1 < KB) gload_lds16(ast + (size_t)(kb+1)*1024, cur ? myl0 : myl1);
    bf16x8 whn = whv, wln = wlv;
    if (kb + 1 < KB){ whn = whp[(kb+1)*64]; wln = wlp[(kb+1)*64]; }
    const unsigned char* rb = cur ? rb1 : rb0;
    bf16x8 a0h = *(const bf16x8*)(rb +        (size_t)lane*16);
    bf16x8 a0l = *(const bf16x8*)(rb + 1024 + (size_t)lane*16);
    bf16x8 a1h = *(const bf16x8*)(rb + 2048 + (size_t)lane*16);
    bf16x8 a1l = *(const bf16x8*)(rb + 3072 + (size_t)lane*16);
    acc0 = MFMA(whv, a0h, acc0);
    acc1 = MFMA(whv, a1h, acc1);
    acc0 = MFMA(wlv, a0h, acc0);
    acc1 = MFMA(wlv, a1h, acc1);
    acc0 = MFMA(whv, a0l, acc0);
    acc1 = MFMA(whv, a1l, acc1);
    __syncthreads();
    whv = whn; wlv = wln;
  }

  const int bb0 = nt*64 + fn0*16 + (lane & 15);
  #pragma unroll
  for (int n = 0; n < 2; n++){
    f32x4 g = n ? acc1 : acc0;
    int b = bb0 + n*16;
    float ig = sigf(g[0]);
    float fg = sigf(g[1]);
    float gg = tanhf(g[2]);
    float og = sigf(g[3]);
    float c2 = fg * c_in[(size_t)b*512 + j0] + ig * gg;
    float h  = og * tanhf(c2);
    c_out[(size_t)b*512 + j0] = c2;
    if (h_f32) h_f32[(size_t)b*512 + j0] = h;
    unsigned short hh = f2bf(h);
    unsigned short hl = f2bf(h - bf2f(hh));
    size_t o0 = pk(b, off0 + j0, KB0);
    out0[o0] = hh; out0[o0 + plane0] = hl;
    if (out1){
      size_t o1 = pk(b, off1 + j0, KB1);
      out1[o1] = hh; out1[o1 + plane1] = hl;
    }
  }
}

// ---------------- z GEMM: [mu;sig](256x512) x hE^T + reparam epilogue ----------------
__global__ __launch_bounds__(64) void zgemm_kernel(
    const bf16x8* __restrict__ Wzh, const bf16x8* __restrict__ Wzl,
    const unsigned short* __restrict__ az, int planeZ,
    const float* __restrict__ mu_b, const float* __restrict__ sig_b,
    const float* __restrict__ eps_t,
    unsigned short* __restrict__ actD, int planeD)
{
  const int fmb = blockIdx.x & 7, cg = blockIdx.x >> 3;
  const int lane = threadIdx.x;
  const bf16x8* wmh = Wzh + (size_t)(fmb    *16)*64 + lane;
  const bf16x8* wml = Wzl + (size_t)(fmb    *16)*64 + lane;
  const bf16x8* wsh = Wzh + (size_t)((fmb+8)*16)*64 + lane;
  const bf16x8* wsl = Wzl + (size_t)((fmb+8)*16)*64 + lane;
  const unsigned short* ab = az + (size_t)cg*8192 + (size_t)lane*8;

  const int r0 = fmb*16 + (lane >> 4)*4;
  float4 bm = *(const float4*)&mu_b[r0];
  float4 bs = *(const float4*)&sig_b[r0];
  f32x4 am = {bm.x, bm.y, bm.z, bm.w};
  f32x4 as = {bs.x, bs.y, bs.z, bs.w};

  #pragma unroll
  for (int kb = 0; kb < 16; kb++){
    bf16x8 ah = *(const bf16x8*)(ab + (size_t)kb*512);
    bf16x8 al = *(const bf16x8*)(ab + planeZ + (size_t)kb*512);
    bf16x8 h0 = wmh[kb*64], l0 = wml[kb*64];
    bf16x8 h1 = wsh[kb*64], l1 = wsl[kb*64];
    am = MFMA(h0, ah, am); am = MFMA(l0, ah, am); am = MFMA(h0, al, am);
    as = MFMA(h1, ah, as); as = MFMA(l1, ah, as); as = MFMA(h1, al, as);
  }

  const int b = cg*16 + (lane & 15);
  float4 ev = *(const float4*)&eps_t[(size_t)b*128 + r0];
  float e[4] = {ev.x, ev.y, ev.z, ev.w};
  union { unsigned short s[4]; uint2 u; } zh, zl;
  #pragma unroll
  for (int i = 0; i < 4; i++){
    float z = am[i] + e[i]*__expf(as[i]);
    unsigned short hi = f2bf(z);
    zh.s[i] = hi;
    zl.s[i] = f2bf(z - bf2f(hi));
  }
  size_t o = pk(b, r0, 20);
  *(uint2*)(actD + o) = zh.u;
  *(uint2*)(actD + planeD + o) = zl.u;
}

// ---------------- fused write(t) + glimpse(t+1) ----------------
// same h_dec and READ_N==WRITE_N==8 => identical filterbank for both ops
__global__ __launch_bounds__(256) void wg_kernel(
    const float* __restrict__ h_dec,
    const float* __restrict__ WwT, const float* __restrict__ write_b,
    const float* __restrict__ attn_W, const float* __restrict__ attn_b,
    const float* __restrict__ canvas_prev, float* __restrict__ canvas_out,
    const float* __restrict__ x,
    unsigned short* __restrict__ rout, int planeE)
{
  __shared__ float hs[512];
  __shared__ float Fx[8*LDF], Fy[8*LDF], pl[8];
  __shared__ float cs[64*LDF];
  __shared__ float img_s[64*LDF];
  __shared__ float P[2][8*LDF];
  __shared__ float ps[4][64], w_s[64];
  __shared__ float tmp[64*8];
  const int b = blockIdx.x, tid = threadIdx.x;

  for (int i = tid; i < 128; i += 256)
    ((float4*)hs)[i] = ((const float4*)(h_dec + (size_t)b*512))[i];
  if (rout){
    const float4* x4 = (const float4*)(x + (size_t)b*4096);
    for (int i = tid; i < 1024; i += 256){
      int row = i >> 4, cb = (i & 15)*4;
      *(float4*)&img_s[row*LDF + cb] = x4[i];
    }
  }
  __syncthreads();
  attn_window(hs, attn_W, attn_b, Fx, Fy, pl);
  float gamma = __expf(pl[4]);

  if (canvas_out){
    {
      int j = tid & 63, part = tid >> 6;
      float s = 0.f;
      int kb = part*128;
      for (int k = 0; k < 128; k++) s += hs[kb + k] * WwT[(kb + k)*64 + j];
      ps[part][j] = s;
    }
    __syncthreads();
    if (tid < 64)
      w_s[tid] = write_b[tid] + ps[0][tid] + ps[1][tid] + ps[2][tid] + ps[3][tid];
    __syncthreads();
    float inv_g = __expf(-pl[4]);
    #pragma unroll
    for (int e = 0; e < 2; e++){
      int gi = e*256 + tid;
      int m = gi & 7, hh = gi >> 3;
      float s = 0.f;
      #pragma unroll
      for (int nn = 0; nn < 8; nn++) s += Fy[nn*LDF + hh] * w_s[nn*8 + m];
      tmp[hh*8 + m] = s;
    }
    __syncthreads();
    for (int e = 0; e < 16; e++){
      int idx = e*256 + tid;
      int hh = idx >> 6, a = idx & 63;
      float s = 0.f;
      #pragma unroll
      for (int m = 0; m < 8; m++) s += tmp[hh*8 + m] * Fx[m*LDF + a];
      float prev = canvas_prev ? canvas_prev[(size_t)b*4096 + idx] : 0.f;
      float cv = prev + s*inv_g;
      canvas_out[(size_t)b*4096 + idx] = cv;
      cs[hh*LDF + a] = cv;
    }
  } else {
    for (int e = 0; e < 16; e++){
      int idx = e*256 + tid;
      cs[(idx >> 6)*LDF + (idx & 63)] = 0.f;
    }
  }
  if (!rout) return;
  __syncthreads();
  for (int e = 0; e < 16; e++){
    int idx = e*256 + tid;
    int hh = idx >> 6, a = idx & 63;
    cs[hh*LDF + a] = sigf(cs[hh*LDF + a]);
  }
  __syncthreads();
  // P[0] = img . Fx^T ; P[1] = sig(canvas) . Fx^T
  #pragma unroll
  for (int e = 0; e < 4; e++){
    int gi = e*256 + tid;
    int d = gi >> 9, rem = gi & 511;
    int m = rem & 7, hh = rem >> 3;
    const float* S = d ? cs : img_s;
    float s = 0.f;
    #pragma unroll
    for (int w4 = 0; w4 < 64; w4 += 4){
      float4 iv = *(const float4*)&S[hh*LDF + w4];
      float4 fv = *(const float4*)&Fx[m*LDF + w4];
      s += iv.x*fv.x + iv.y*fv.y + iv.z*fv.z + iv.w*fv.w;
    }
    P[d][m*LDF + hh] = s;
  }
  __syncthreads();
  if (tid < 128){
    int d = tid >> 6, l = tid & 63;
    int n = l >> 3, m = l & 7;
    float s = 0.f;
    #pragma unroll
    for (int h4 = 0; h4 < 64; h4 += 4){
      float4 fv = *(const float4*)&Fy[n*LDF + h4];
      float4 pv = *(const float4*)&P[d][m*LDF + h4];
      s += fv.x*pv.x + fv.y*pv.y + fv.z*pv.z + fv.w*pv.w;
    }
    tmp[d*64 + l] = s;
  }
  __syncthreads();
  if (tid < 64){
    float g1 = tmp[tid]*gamma;                   // r for img, col = tid
    float g2 = (tmp[tid] - tmp[64 + tid])*gamma; // r for x_hat, col = 64+tid
    unsigned short h1 = f2bf(g1), l1 = f2bf(g1 - bf2f(h1));
    unsigned short h2 = f2bf(g2), l2 = f2bf(g2 - bf2f(h2));
    size_t o1 = pk(b, tid, 36);
    size_t o2 = pk(b, 64 + tid, 36);
    rout[o1] = h1; rout[o1 + planeE] = l1;
    rout[o2] = h2; rout[o2 + planeE] = l2;
  }
}

// ---------------- host launcher ----------------
extern "C" void kernel_launch(void* const* d_in, const int* in_sizes, int n_in,
                              void* d_out, int out_size, void* d_ws, size_t ws_size,
                              hipStream_t stream)
{
  (void)in_sizes; (void)n_in; (void)out_size; (void)ws_size;
  const float* x       = (const float*)d_in[0];
  const float* eps     = (const float*)d_in[1];
  const float* encWih  = (const float*)d_in[2];
  const float* encWhh  = (const float*)d_in[3];
  const float* enc_b   = (const float*)d_in[4];
  const float* muW     = (const float*)d_in[5];
  const float* mu_b    = (const float*)d_in[6];
  const float* sigW    = (const float*)d_in[7];
  const float* sig_b   = (const float*)d_in[8];
  const float* decWih  = (const float*)d_in[9];
  const float* decWhh  = (const float*)d_in[10];
  const float* dec_b   = (const float*)d_in[11];
  const float* writeW  = (const float*)d_in[12];
  const float* write_b = (const float*)d_in[13];
  const float* attnW   = (const float*)d_in[14];
  const float* attn_b  = (const float*)d_in[15];
  float* out = (float*)d_out;

  char* p = (char*)d_ws;
  auto alloc = [&](size_t bytes){ char* r = p; p += (bytes + 255) & ~(size_t)255; return r; };

  const int KE = 1152, KD = 640;
  const int PE = 512*KE, PD = 512*KD, PZ = 512*512;
  const int T8E = 128*36*64, T8D = 128*20*64;

  unsigned short* WpEh = (unsigned short*)alloc((size_t)T8E*16);
  unsigned short* WpEl = (unsigned short*)alloc((size_t)T8E*16);
  unsigned short* WpDh = (unsigned short*)alloc((size_t)T8D*16);
  unsigned short* WpDl = (unsigned short*)alloc((size_t)T8D*16);
  unsigned short* Wzh  = (unsigned short*)alloc(16384*16);
  unsigned short* Wzl  = (unsigned short*)alloc(16384*16);
  float* bE  = (float*)alloc(2048*4);
  float* bD  = (float*)alloc(2048*4);
  float* WwT = (float*)alloc(512*64*4);
  // zero-init region
  char* z0 = p;
  unsigned short* actE0 = (unsigned short*)alloc((size_t)2*PE*2);
  unsigned short* actD0 = (unsigned short*)alloc((size_t)2*PD*2);
  float* hDf = (float*)alloc(512*512*4);
  float* cE0 = (float*)alloc(512*512*4);
  float* cD0 = (float*)alloc(512*512*4);
  size_t zbytes = (size_t)(p - z0);
  unsigned short* actE1 = (unsigned short*)alloc((size_t)2*PE*2);
  unsigned short* actD1 = (unsigned short*)alloc((size_t)2*PD*2);
  unsigned short* AZ    = (unsigned short*)alloc((size_t)2*PZ*2);
  float* cE1 = (float*)alloc(512*512*4);
  float* cD1 = (float*)alloc(512*512*4);

  unsigned short* actE[2] = { actE0, actE1 };
  unsigned short* actD[2] = { actD0, actD1 };
  float* cEf[2] = { cE0, cE1 };
  float* cDf[2] = { cD0, cD1 };

  int tot;
  tot = T8E;   pack_w_mfma<<<(tot+255)/256,256,0,stream>>>(encWih, encWhh, 640, KE, WpEh, WpEl, tot);
  tot = T8D;   pack_w_mfma<<<(tot+255)/256,256,0,stream>>>(decWih, decWhh, 128, KD, WpDh, WpDl, tot);
  pack_wz_mfma<<<64,256,0,stream>>>(muW, sigW, Wzh, Wzl);
  tot = 2048;  reorder_gates<<<(tot+255)/256,256,0,stream>>>(enc_b, bE, 512, 1, tot);
  tot = 2048;  reorder_gates<<<(tot+255)/256,256,0,stream>>>(dec_b, bD, 512, 1, tot);
  tot = 512*64; transpose_ww<<<(tot+255)/256,256,0,stream>>>(writeW, WwT);
  tot = (int)(zbytes/4); zero_f<<<(tot+255)/256,256,0,stream>>>((float*)z0, tot);

  // pre-loop glimpse (t=0): zero canvas, zero h_dec
  wg_kernel<<<512,256,0,stream>>>(hDf, WwT, write_b, attnW, attn_b,
                                  nullptr, nullptr, x, actE[0], PE);

  for (int t = 0; t < 16; t++){
    int cur = t & 1, nxt = cur ^ 1;

    mfma_gemm_lstm<36><<<256,512,0,stream>>>(
        (const bf16x8*)WpEh, (const bf16x8*)WpEl, actE[cur], PE,
        (const float4*)bE, cEf[cur], nullptr, cEf[nxt],
        AZ, 16, 0, PZ,
        actE[nxt], 36, 640, PE);

    zgemm_kernel<<<256,64,0,stream>>>(
        (const bf16x8*)Wzh, (const bf16x8*)Wzl, AZ, PZ,
        mu_b, sig_b, eps + (size_t)t*65536, actD[cur], PD);

    mfma_gemm_lstm<20><<<256,512,0,stream>>>(
        (const bf16x8*)WpDh, (const bf16x8*)WpDl, actD[cur], PD,
        (const float4*)bD, cDf[cur], hDf, cDf[nxt],
        actE[nxt], 36, 128, PE,
        actD[nxt], 20, 128, PD);

    wg_kernel<<<512,256,0,stream>>>(hDf, WwT, write_b, attnW, attn_b,
                                    t ? (out + (size_t)(t-1)*2097152) : nullptr,
                                    out + (size_t)t*2097152, x,
                                    (t < 15) ? actE[nxt] : nullptr, PE);
  }
}

// Round 6
// 933.416 us; speedup vs baseline: 2.4650x; 1.1694x over previous
//
#include <hip/hip_runtime.h>

#define LDF 68
#define EPSF 1e-8f
#define MFMA(A,B,C) __builtin_amdgcn_mfma_f32_16x16x32_bf16((A),(B),(C),0,0,0)

typedef __attribute__((ext_vector_type(8))) short bf16x8;
typedef __attribute__((ext_vector_type(4))) float f32x4;

__device__ __forceinline__ float sigf(float x){ return 1.0f/(1.0f + __expf(-x)); }

__device__ __forceinline__ unsigned short f2bf(float f){
  unsigned u = __float_as_uint(f);
  u += 0x7FFFu + ((u >> 16) & 1u);
  return (unsigned short)(u >> 16);
}
__device__ __forceinline__ float bf2f(unsigned short s){
  return __uint_as_float((unsigned)s << 16);
}

// packed-activation element index (u16 units) within one plane
__device__ __forceinline__ size_t pk(int b, int col, int KB){
  return ((((size_t)((b>>4)*KB + (col>>5)))*64) + (size_t)((b&15) + (((col>>3)&3)<<4)))*8 + (col&7);
}

__device__ __forceinline__ void gload_lds16(const void* g, void* l){
  __builtin_amdgcn_global_load_lds(
      (const __attribute__((address_space(1))) void*)g,
      (__attribute__((address_space(3))) void*)l, 16, 0, 0);
}

// ---------------- init kernels ----------------
__global__ void reorder_gates(const float* __restrict__ src, float* __restrict__ dst,
                              int H, int K, int total){
  int idx = blockIdx.x*256 + threadIdx.x;
  if (idx >= total) return;
  int row = idx / K;
  int col = idx - row*K;
  int j = row >> 2, g = row & 3;
  dst[idx] = src[(size_t)(g*H + j)*K + col];
}

// pack gate-reordered [2048 x K_tot] weights (f32: Wih|Whh) into bf16 hi+lo MFMA frags
__global__ void pack_w_mfma(const float* __restrict__ Wih, const float* __restrict__ Whh,
                            int K_ih, int K_tot,
                            unsigned short* __restrict__ dhi, unsigned short* __restrict__ dlo,
                            int total8){
  int idx = blockIdx.x*256 + threadIdx.x;
  if (idx >= total8) return;
  int lane = idx & 63;
  int rest = idx >> 6;
  int KB = K_tot >> 5;
  int kb = rest % KB;
  int fm = rest / KB;
  int rr = fm*16 + (lane & 15);
  int orow = (rr & 3)*512 + (rr >> 2);     // gate reorder fused
  int k0 = kb*32 + (lane >> 4)*8;
  union { unsigned short s[8]; uint4 u; } vh, vl;
  #pragma unroll
  for (int i = 0; i < 8; i++){
    int k = k0 + i;
    float f = (k < K_ih) ? Wih[(size_t)orow*K_ih + k]
                         : Whh[(size_t)orow*512 + (k - K_ih)];
    unsigned short hi = f2bf(f);
    vh.s[i] = hi;
    vl.s[i] = f2bf(f - bf2f(hi));
  }
  *(uint4*)(dhi + (size_t)idx*8) = vh.u;
  *(uint4*)(dlo + (size_t)idx*8) = vl.u;
}

// pack [mu_W;sig_W] (256x512) into bf16 hi+lo frags, no gate reorder
__global__ void pack_wz_mfma(const float* __restrict__ muW, const float* __restrict__ sigW,
                             unsigned short* __restrict__ dhi, unsigned short* __restrict__ dlo){
  int idx = blockIdx.x*256 + threadIdx.x;
  if (idx >= 16384) return;
  int lane = idx & 63, rest = idx >> 6;
  int kb = rest & 15, fmf = rest >> 4;
  int row = fmf*16 + (lane & 15);
  const float* src = (row < 128) ? (muW + (size_t)row*512) : (sigW + (size_t)(row-128)*512);
  int k0 = kb*32 + (lane >> 4)*8;
  union { unsigned short s[8]; uint4 u; } vh, vl;
  #pragma unroll
  for (int i = 0; i < 8; i++){
    float f = src[k0 + i];
    unsigned short hi = f2bf(f);
    vh.s[i] = hi;
    vl.s[i] = f2bf(f - bf2f(hi));
  }
  *(uint4*)(dhi + (size_t)idx*8) = vh.u;
  *(uint4*)(dlo + (size_t)idx*8) = vl.u;
}

__global__ void transpose_ww(const float* __restrict__ W, float* __restrict__ dst){
  int idx = blockIdx.x*256 + threadIdx.x;
  if (idx >= 512*64) return;
  int k = idx >> 6, n = idx & 63;
  dst[idx] = W[n*512 + k];
}

__global__ void zero_f(float* p, int n){
  int idx = blockIdx.x*256 + threadIdx.x;
  if (idx < n) p[idx] = 0.f;
}

// ---------------- attention window helper ----------------
__device__ void attn_window(const float* __restrict__ h,
                            const float* __restrict__ attn_W,
                            const float* __restrict__ attn_b,
                            float* Fx, float* Fy, float* pl)
{
  int tid = threadIdx.x;
  int lane = tid & 63, wid = tid >> 6;
  for (int q = wid; q < 5; q += 4){
    float s = 0.f;
    for (int k = lane; k < 512; k += 64) s += h[k]*attn_W[q*512 + k];
    for (int m = 32; m; m >>= 1) s += __shfl_xor(s, m);
    if (lane == 0) pl[q] = s + attn_b[q];
  }
  __syncthreads();
  float gx    = 32.5f*(pl[0] + 1.f);
  float gy    = 32.5f*(pl[1] + 1.f);
  float s2    = __expf(pl[2]);
  float delta = 9.f*__expf(pl[3]);
  float inv2  = 1.f/(2.f*s2);
  int n = tid >> 5, a = tid & 31;
  float mux = gx + ((float)n - 4.5f)*delta;
  float muy = gy + ((float)n - 4.5f)*delta;
  float dx0 = (float)a      - mux, dx1 = (float)(a+32) - mux;
  float dy0 = (float)a      - muy, dy1 = (float)(a+32) - muy;
  float e0 = __expf(-dx0*dx0*inv2), e1 = __expf(-dx1*dx1*inv2);
  float f0 = __expf(-dy0*dy0*inv2), f1 = __expf(-dy1*dy1*inv2);
  float sx = e0 + e1, sy = f0 + f1;
  for (int m = 16; m; m >>= 1){ sx += __shfl_xor(sx, m); sy += __shfl_xor(sy, m); }
  float rx = 1.f/(sx + EPSF), ry = 1.f/(sy + EPSF);
  Fx[n*LDF + a]      = e0*rx;  Fx[n*LDF + a + 32] = e1*rx;
  Fy[n*LDF + a]      = f0*ry;  Fy[n*LDF + a + 32] = f1*ry;
  __syncthreads();
}

// ---------------- MFMA GEMM (split hi/lo) + fused LSTM epilogue ----------------
// 64x64 tile, 8 waves; acts LDS-staged via 3-deep counted-vmcnt pipeline (T3/T4);
// weights reg-direct with 2-ahead prefetch.
template<int KB>
__global__ __launch_bounds__(512) void mfma_gemm_lstm(
    const bf16x8* __restrict__ Wh, const bf16x8* __restrict__ Wl,
    const unsigned short* __restrict__ act, int actPlane,
    const float4* __restrict__ bias4, const float* __restrict__ c_in,
    float* __restrict__ h_f32, float* __restrict__ c_out,
    unsigned short* __restrict__ out0, int KB0, int off0, int plane0,
    unsigned short* __restrict__ out1, int KB1, int off1, int plane1)
{
  __shared__ __align__(16) unsigned char lds[3][8192];
  const int tid = threadIdx.x, lane = tid & 63, w = tid >> 6;
  const int mt = blockIdx.x & 31, nt = blockIdx.x >> 5;
  const int fm = w & 3, fn0 = (w >> 2) << 1;

  const bf16x8* whp = Wh + ((size_t)(mt*4+fm)*KB)*64 + lane;
  const bf16x8* wlp = Wl + ((size_t)(mt*4+fm)*KB)*64 + lane;

  // this wave stages chunk (fn = w>>1, plane = w&1), 1 KB per kb
  const char* ast = (const char*)act + (size_t)(w & 1)*((size_t)actPlane*2)
                  + ((size_t)(nt*4 + (w >> 1))*KB)*1024 + (size_t)lane*16;

  const int j0 = (mt*4+fm)*4 + (lane >> 4);   // unit id
  float4 bb = bias4[j0];
  f32x4 acc0 = {bb.x, bb.y, bb.z, bb.w};
  f32x4 acc1 = acc0;

  // prologue: group kb=0, then group kb=1 (pinned order for vmcnt counting)
  gload_lds16(ast, (char*)&lds[0][w*1024]);
  bf16x8 whA = whp[0], wlA = wlp[0];
  __builtin_amdgcn_sched_barrier(0);
  asm volatile("" ::: "memory");
  gload_lds16(ast + 1024, (char*)&lds[1][w*1024]);
  bf16x8 whB = whp[64], wlB = wlp[64];
  __builtin_amdgcn_sched_barrier(0);
  asm volatile("" ::: "memory");

  const size_t rdoff = (size_t)fn0*2048 + (size_t)lane*16;

  #pragma unroll
  for (int kb = 0; kb < KB; kb++){
    // my gl(kb)+w(kb) must be landed; gl/w(kb+1) (3 ops) may stay in flight
    asm volatile("s_waitcnt vmcnt(3)" ::: "memory");
    __builtin_amdgcn_s_barrier();
    asm volatile("" ::: "memory");
    __builtin_amdgcn_sched_barrier(0);
    bf16x8 whC = whA, wlC = wlA;           // dead in tail iters
    if (kb + 2 < KB){
      gload_lds16(ast + (size_t)(kb+2)*1024, (char*)&lds[(kb+2)%3][w*1024]);
      whC = whp[(kb+2)*64]; wlC = wlp[(kb+2)*64];
    }
    const unsigned char* rb = &lds[kb%3][0] + rdoff;
    bf16x8 a0h = *(const bf16x8*)(rb);
    bf16x8 a0l = *(const bf16x8*)(rb + 1024);
    bf16x8 a1h = *(const bf16x8*)(rb + 2048);
    bf16x8 a1l = *(const bf16x8*)(rb + 3072);
    acc0 = MFMA(whA, a0h, acc0);
    acc1 = MFMA(whA, a1h, acc1);
    acc0 = MFMA(wlA, a0h, acc0);
    acc1 = MFMA(wlA, a1h, acc1);
    acc0 = MFMA(whA, a0l, acc0);
    acc1 = MFMA(whA, a1l, acc1);
    whA = whB; wlA = wlB; whB = whC; wlB = wlC;
  }

  const int bb0 = nt*64 + fn0*16 + (lane & 15);
  #pragma unroll
  for (int n = 0; n < 2; n++){
    f32x4 g = n ? acc1 : acc0;
    int b = bb0 + n*16;
    float ig = sigf(g[0]);
    float fg = sigf(g[1]);
    float gg = tanhf(g[2]);
    float og = sigf(g[3]);
    float c2 = fg * c_in[(size_t)b*512 + j0] + ig * gg;
    float h  = og * tanhf(c2);
    c_out[(size_t)b*512 + j0] = c2;
    if (h_f32) h_f32[(size_t)b*512 + j0] = h;
    unsigned short hh = f2bf(h);
    unsigned short hl = f2bf(h - bf2f(hh));
    size_t o0 = pk(b, off0 + j0, KB0);
    out0[o0] = hh; out0[o0 + plane0] = hl;
    if (out1){
      size_t o1 = pk(b, off1 + j0, KB1);
      out1[o1] = hh; out1[o1 + plane1] = hl;
    }
  }
}

// ---------------- z GEMM: [mu;sig](256x512) x hE^T + reparam epilogue ----------------
__global__ __launch_bounds__(64) void zgemm_kernel(
    const bf16x8* __restrict__ Wzh, const bf16x8* __restrict__ Wzl,
    const unsigned short* __restrict__ az, int planeZ,
    const float* __restrict__ mu_b, const float* __restrict__ sig_b,
    const float* __restrict__ eps_t,
    unsigned short* __restrict__ actD, int planeD)
{
  const int fmb = blockIdx.x & 7, cg = blockIdx.x >> 3;
  const int lane = threadIdx.x;
  const bf16x8* wmh = Wzh + (size_t)(fmb    *16)*64 + lane;
  const bf16x8* wml = Wzl + (size_t)(fmb    *16)*64 + lane;
  const bf16x8* wsh = Wzh + (size_t)((fmb+8)*16)*64 + lane;
  const bf16x8* wsl = Wzl + (size_t)((fmb+8)*16)*64 + lane;
  const unsigned short* ab = az + (size_t)cg*8192 + (size_t)lane*8;

  const int r0 = fmb*16 + (lane >> 4)*4;
  float4 bm = *(const float4*)&mu_b[r0];
  float4 bs = *(const float4*)&sig_b[r0];
  f32x4 am = {bm.x, bm.y, bm.z, bm.w};
  f32x4 as = {bs.x, bs.y, bs.z, bs.w};

  #pragma unroll
  for (int kb = 0; kb < 16; kb++){
    bf16x8 ah = *(const bf16x8*)(ab + (size_t)kb*512);
    bf16x8 al = *(const bf16x8*)(ab + planeZ + (size_t)kb*512);
    bf16x8 h0 = wmh[kb*64], l0 = wml[kb*64];
    bf16x8 h1 = wsh[kb*64], l1 = wsl[kb*64];
    am = MFMA(h0, ah, am); am = MFMA(l0, ah, am); am = MFMA(h0, al, am);
    as = MFMA(h1, ah, as); as = MFMA(l1, ah, as); as = MFMA(h1, al, as);
  }

  const int b = cg*16 + (lane & 15);
  float4 ev = *(const float4*)&eps_t[(size_t)b*128 + r0];
  float e[4] = {ev.x, ev.y, ev.z, ev.w};
  union { unsigned short s[4]; uint2 u; } zh, zl;
  #pragma unroll
  for (int i = 0; i < 4; i++){
    float z = am[i] + e[i]*__expf(as[i]);
    unsigned short hi = f2bf(z);
    zh.s[i] = hi;
    zl.s[i] = f2bf(z - bf2f(hi));
  }
  size_t o = pk(b, r0, 20);
  *(uint2*)(actD + o) = zh.u;
  *(uint2*)(actD + planeD + o) = zl.u;
}

// ---------------- fused write(t) + glimpse(t+1) ----------------
// same h_dec and READ_N==WRITE_N==8 => identical filterbank for both ops
__global__ __launch_bounds__(256) void wg_kernel(
    const float* __restrict__ h_dec,
    const float* __restrict__ WwT, const float* __restrict__ write_b,
    const float* __restrict__ attn_W, const float* __restrict__ attn_b,
    const float* __restrict__ canvas_prev, float* __restrict__ canvas_out,
    const float* __restrict__ x,
    unsigned short* __restrict__ rout, int planeE)
{
  __shared__ float hs[512];
  __shared__ float Fx[8*LDF], Fy[8*LDF], pl[8];
  __shared__ float cs[64*LDF];
  __shared__ float img_s[64*LDF];
  __shared__ float P[2][8*LDF];
  __shared__ float ps[4][64], w_s[64];
  __shared__ float tmp[64*8];
  const int b = blockIdx.x, tid = threadIdx.x;

  for (int i = tid; i < 128; i += 256)
    ((float4*)hs)[i] = ((const float4*)(h_dec + (size_t)b*512))[i];
  if (rout){
    const float4* x4 = (const float4*)(x + (size_t)b*4096);
    for (int i = tid; i < 1024; i += 256){
      int row = i >> 4, cb = (i & 15)*4;
      *(float4*)&img_s[row*LDF + cb] = x4[i];
    }
  }
  __syncthreads();
  attn_window(hs, attn_W, attn_b, Fx, Fy, pl);
  float gamma = __expf(pl[4]);

  if (canvas_out){
    {
      int j = tid & 63, part = tid >> 6;
      float s = 0.f;
      int kb = part*128;
      for (int k = 0; k < 128; k++) s += hs[kb + k] * WwT[(kb + k)*64 + j];
      ps[part][j] = s;
    }
    __syncthreads();
    if (tid < 64)
      w_s[tid] = write_b[tid] + ps[0][tid] + ps[1][tid] + ps[2][tid] + ps[3][tid];
    __syncthreads();
    float inv_g = __expf(-pl[4]);
    #pragma unroll
    for (int e = 0; e < 2; e++){
      int gi = e*256 + tid;
      int m = gi & 7, hh = gi >> 3;
      float s = 0.f;
      #pragma unroll
      for (int nn = 0; nn < 8; nn++) s += Fy[nn*LDF + hh] * w_s[nn*8 + m];
      tmp[hh*8 + m] = s;
    }
    __syncthreads();
    for (int e = 0; e < 16; e++){
      int idx = e*256 + tid;
      int hh = idx >> 6, a = idx & 63;
      float s = 0.f;
      #pragma unroll
      for (int m = 0; m < 8; m++) s += tmp[hh*8 + m] * Fx[m*LDF + a];
      float prev = canvas_prev ? canvas_prev[(size_t)b*4096 + idx] : 0.f;
      float cv = prev + s*inv_g;
      canvas_out[(size_t)b*4096 + idx] = cv;
      cs[hh*LDF + a] = cv;
    }
  } else {
    for (int e = 0; e < 16; e++){
      int idx = e*256 + tid;
      cs[(idx >> 6)*LDF + (idx & 63)] = 0.f;
    }
  }
  if (!rout) return;
  __syncthreads();
  for (int e = 0; e < 16; e++){
    int idx = e*256 + tid;
    int hh = idx >> 6, a = idx & 63;
    cs[hh*LDF + a] = sigf(cs[hh*LDF + a]);
  }
  __syncthreads();
  // P[0] = img . Fx^T ; P[1] = sig(canvas) . Fx^T
  #pragma unroll
  for (int e = 0; e < 4; e++){
    int gi = e*256 + tid;
    int d = gi >> 9, rem = gi & 511;
    int m = rem & 7, hh = rem >> 3;
    const float* S = d ? cs : img_s;
    float s = 0.f;
    #pragma unroll
    for (int w4 = 0; w4 < 64; w4 += 4){
      float4 iv = *(const float4*)&S[hh*LDF + w4];
      float4 fv = *(const float4*)&Fx[m*LDF + w4];
      s += iv.x*fv.x + iv.y*fv.y + iv.z*fv.z + iv.w*fv.w;
    }
    P[d][m*LDF + hh] = s;
  }
  __syncthreads();
  if (tid < 128){
    int d = tid >> 6, l = tid & 63;
    int n = l >> 3, m = l & 7;
    float s = 0.f;
    #pragma unroll
    for (int h4 = 0; h4 < 64; h4 += 4){
      float4 fv = *(const float4*)&Fy[n*LDF + h4];
      float4 pv = *(const float4*)&P[d][m*LDF + h4];
      s += fv.x*pv.x + fv.y*pv.y + fv.z*pv.z + fv.w*pv.w;
    }
    tmp[d*64 + l] = s;
  }
  __syncthreads();
  if (tid < 64){
    float g1 = tmp[tid]*gamma;                   // r for img, col = tid
    float g2 = (tmp[tid] - tmp[64 + tid])*gamma; // r for x_hat, col = 64+tid
    unsigned short h1 = f2bf(g1), l1 = f2bf(g1 - bf2f(h1));
    unsigned short h2 = f2bf(g2), l2 = f2bf(g2 - bf2f(h2));
    size_t o1 = pk(b, tid, 36);
    size_t o2 = pk(b, 64 + tid, 36);
    rout[o1] = h1; rout[o1 + planeE] = l1;
    rout[o2] = h2; rout[o2 + planeE] = l2;
  }
}

// ---------------- host launcher ----------------
extern "C" void kernel_launch(void* const* d_in, const int* in_sizes, int n_in,
                              void* d_out, int out_size, void* d_ws, size_t ws_size,
                              hipStream_t stream)
{
  (void)in_sizes; (void)n_in; (void)out_size; (void)ws_size;
  const float* x       = (const float*)d_in[0];
  const float* eps     = (const float*)d_in[1];
  const float* encWih  = (const float*)d_in[2];
  const float* encWhh  = (const float*)d_in[3];
  const float* enc_b   = (const float*)d_in[4];
  const float* muW     = (const float*)d_in[5];
  const float* mu_b    = (const float*)d_in[6];
  const float* sigW    = (const float*)d_in[7];
  const float* sig_b   = (const float*)d_in[8];
  const float* decWih  = (const float*)d_in[9];
  const float* decWhh  = (const float*)d_in[10];
  const float* dec_b   = (const float*)d_in[11];
  const float* writeW  = (const float*)d_in[12];
  const float* write_b = (const float*)d_in[13];
  const float* attnW   = (const float*)d_in[14];
  const float* attn_b  = (const float*)d_in[15];
  float* out = (float*)d_out;

  char* p = (char*)d_ws;
  auto alloc = [&](size_t bytes){ char* r = p; p += (bytes + 255) & ~(size_t)255; return r; };

  const int KE = 1152, KD = 640;
  const int PE = 512*KE, PD = 512*KD, PZ = 512*512;
  const int T8E = 128*36*64, T8D = 128*20*64;

  unsigned short* WpEh = (unsigned short*)alloc((size_t)T8E*16);
  unsigned short* WpEl = (unsigned short*)alloc((size_t)T8E*16);
  unsigned short* WpDh = (unsigned short*)alloc((size_t)T8D*16);
  unsigned short* WpDl = (unsigned short*)alloc((size_t)T8D*16);
  unsigned short* Wzh  = (unsigned short*)alloc(16384*16);
  unsigned short* Wzl  = (unsigned short*)alloc(16384*16);
  float* bE  = (float*)alloc(2048*4);
  float* bD  = (float*)alloc(2048*4);
  float* WwT = (float*)alloc(512*64*4);
  // zero-init region
  char* z0 = p;
  unsigned short* actE0 = (unsigned short*)alloc((size_t)2*PE*2);
  unsigned short* actD0 = (unsigned short*)alloc((size_t)2*PD*2);
  float* hDf = (float*)alloc(512*512*4);
  float* cE0 = (float*)alloc(512*512*4);
  float* cD0 = (float*)alloc(512*512*4);
  size_t zbytes = (size_t)(p - z0);
  unsigned short* actE1 = (unsigned short*)alloc((size_t)2*PE*2);
  unsigned short* actD1 = (unsigned short*)alloc((size_t)2*PD*2);
  unsigned short* AZ    = (unsigned short*)alloc((size_t)2*PZ*2);
  float* cE1 = (float*)alloc(512*512*4);
  float* cD1 = (float*)alloc(512*512*4);

  unsigned short* actE[2] = { actE0, actE1 };
  unsigned short* actD[2] = { actD0, actD1 };
  float* cEf[2] = { cE0, cE1 };
  float* cDf[2] = { cD0, cD1 };

  int tot;
  tot = T8E;   pack_w_mfma<<<(tot+255)/256,256,0,stream>>>(encWih, encWhh, 640, KE, WpEh, WpEl, tot);
  tot = T8D;   pack_w_mfma<<<(tot+255)/256,256,0,stream>>>(decWih, decWhh, 128, KD, WpDh, WpDl, tot);
  pack_wz_mfma<<<64,256,0,stream>>>(muW, sigW, Wzh, Wzl);
  tot = 2048;  reorder_gates<<<(tot+255)/256,256,0,stream>>>(enc_b, bE, 512, 1, tot);
  tot = 2048;  reorder_gates<<<(tot+255)/256,256,0,stream>>>(dec_b, bD, 512, 1, tot);
  tot = 512*64; transpose_ww<<<(tot+255)/256,256,0,stream>>>(writeW, WwT);
  tot = (int)(zbytes/4); zero_f<<<(tot+255)/256,256,0,stream>>>((float*)z0, tot);

  // pre-loop glimpse (t=0): zero canvas, zero h_dec
  wg_kernel<<<512,256,0,stream>>>(hDf, WwT, write_b, attnW, attn_b,
                                  nullptr, nullptr, x, actE[0], PE);

  for (int t = 0; t < 16; t++){
    int cur = t & 1, nxt = cur ^ 1;

    mfma_gemm_lstm<36><<<256,512,0,stream>>>(
        (const bf16x8*)WpEh, (const bf16x8*)WpEl, actE[cur], PE,
        (const float4*)bE, cEf[cur], nullptr, cEf[nxt],
        AZ, 16, 0, PZ,
        actE[nxt], 36, 640, PE);

    zgemm_kernel<<<256,64,0,stream>>>(
        (const bf16x8*)Wzh, (const bf16x8*)Wzl, AZ, PZ,
        mu_b, sig_b, eps + (size_t)t*65536, actD[cur], PD);

    mfma_gemm_lstm<20><<<256,512,0,stream>>>(
        (const bf16x8*)WpDh, (const bf16x8*)WpDl, actD[cur], PD,
        (const float4*)bD, cDf[cur], hDf, cDf[nxt],
        actE[nxt], 36, 128, PE,
        actD[nxt], 20, 128, PD);

    wg_kernel<<<512,256,0,stream>>>(hDf, WwT, write_b, attnW, attn_b,
                                    t ? (out + (size_t)(t-1)*2097152) : nullptr,
                                    out + (size_t)t*2097152, x,
                                    (t < 15) ? actE[nxt] : nullptr, PE);
  }
}